// Round 1
// baseline (1105.199 us; speedup 1.0000x reference)
//
#include <hip/hip_runtime.h>

#define NT 128      // num tags
#define SEQ 1024    // sequence length
#define NB 256      // batch

// One block per batch element. 256 threads = 4 waves.
// thread t: j = t & 127 (output column), ih = t >> 7 (which half of i-range).
// Each thread holds E[ih*64 + r][j] = exp(trans[(ih*64+r)*128 + j]) in registers.
__global__ __launch_bounds__(256) void crf_scan_kernel(
    const float* __restrict__ emissions,    // [B,S,T]
    const float* __restrict__ masks,        // [B,S]
    const int*   __restrict__ tags,         // [B,S]
    const float* __restrict__ transitions,  // [T,T] (log domain)
    const float* __restrict__ start_t,      // [T]
    const float* __restrict__ end_t,        // [T]
    float* __restrict__ out_per_batch)      // [B]
{
    const int b  = blockIdx.x;
    const int t  = threadIdx.x;
    const int j  = t & (NT - 1);
    const int ih = t >> 7;           // 0 or 1

    __shared__ float4 p4[NT / 4];    // current scaled probabilities (fp32, max-normalized)
    __shared__ float  red[NT];       // partial sums from ih==1 half
    __shared__ float  msk_s[SEQ];    // masks for this batch
    __shared__ float  mx_s[2];       // cross-wave max scratch
    __shared__ float  scratch[16];   // final reductions
    float* p_f = (float*)p4;

    // ---- one-time init ----
    // E fragment into registers (prob domain)
    float E_reg[64];
    #pragma unroll
    for (int r = 0; r < 64; ++r)
        E_reg[r] = __expf(transitions[(ih * 64 + r) * NT + j]);

    // masks into LDS
    for (int s = t; s < SEQ; s += 256)
        msk_s[s] = masks[b * SEQ + s];

    // alpha0 = start_transitions  ->  p = exp(start), offset = 0
    if (t < NT) p_f[j] = __expf(start_t[j]);
    float offset = 0.0f;

    const size_t ebase = (size_t)b * SEQ * NT;
    float em_cur = (ih == 0) ? emissions[ebase + j] : 0.0f;

    __syncthreads();

    // ---- sequential scan over S ----
    for (int s = 0; s < SEQ; ++s) {
        // prefetch next step's emission (has the whole matvec to land)
        float em_nxt = 0.0f;
        if (ih == 0 && s + 1 < SEQ)
            em_nxt = emissions[ebase + (size_t)(s + 1) * NT + j];

        // matvec half: acc = sum_{r} p[ih*64 + r] * E[ih*64 + r][j]
        // p read as all-lanes-same-address float4 broadcasts; E from registers.
        const float4* pch = &p4[ih * 16];
        float a0 = 0.f, a1 = 0.f, a2 = 0.f, a3 = 0.f;
        #pragma unroll
        for (int c = 0; c < 16; ++c) {
            float4 pv = pch[c];
            a0 += pv.x * E_reg[4 * c + 0];
            a1 += pv.y * E_reg[4 * c + 1];
            a2 += pv.z * E_reg[4 * c + 2];
            a3 += pv.w * E_reg[4 * c + 3];
        }
        float acc = (a0 + a1) + (a2 + a3);

        // combine halves
        if (ih == 1) red[j] = acc;
        __syncthreads();

        float v = 0.0f;
        if (ih == 0) {
            float q = acc + red[j];
            v = q * __expf(em_cur);              // apply emission in prob domain
            // wave-level max over 64 lanes (waves 0 and 1 cover j=0..127)
            float m = v;
            #pragma unroll
            for (int off = 32; off > 0; off >>= 1)
                m = fmaxf(m, __shfl_xor(m, off, 64));
            if ((t & 63) == 0) mx_s[t >> 6] = m;
        }
        __syncthreads();

        float mx = fmaxf(mx_s[0], mx_s[1]);
        bool upd = msk_s[s] > 0.0f;              // block-uniform
        if (ih == 0 && upd)
            p_f[j] = v * (1.0f / mx);            // renormalize so max(p)=1
        if (upd)
            offset += __logf(mx);
        em_cur = em_nxt;
        __syncthreads();
    }

    // ---- log_z = offset + log( sum_j p_j * exp(end_j) ) ----
    if (ih == 0) {
        float term = p_f[j] * __expf(end_t[j]);
        #pragma unroll
        for (int off = 32; off > 0; off >>= 1)
            term += __shfl_xor(term, off, 64);
        if ((t & 63) == 0) mx_s[t >> 6] = term;
    }
    __syncthreads();
    float log_z = offset + __logf(mx_s[0] + mx_s[1]);

    // ---- gold-path score ----
    const int tbase = b * SEQ;
    float sc = 0.0f, sm = 0.0f;
    for (int s = t; s < SEQ; s += 256) {
        float m = msk_s[s];
        sm += m;
        int tg = tags[tbase + s];
        if (s < SEQ - 1) {
            int tg1 = tags[tbase + s + 1];
            sc += emissions[ebase + (size_t)s * NT + tg] * m;
            sc += transitions[tg * NT + tg1] * msk_s[s + 1];
        }
    }
    // block reduction of sc, sm
    #pragma unroll
    for (int off = 32; off > 0; off >>= 1) {
        sc += __shfl_xor(sc, off, 64);
        sm += __shfl_xor(sm, off, 64);
    }
    int w = t >> 6;
    if ((t & 63) == 0) { scratch[w] = sc; scratch[8 + w] = sm; }
    __syncthreads();

    if (t == 0) {
        float SC = scratch[0] + scratch[1] + scratch[2] + scratch[3];
        float SM = scratch[8] + scratch[9] + scratch[10] + scratch[11];
        int tg0 = tags[tbase];
        int tgl = tags[tbase + SEQ - 1];
        SC += start_t[tg0];
        int last_ix = (int)fmaxf(SM - 1.0f, 0.0f);
        float ml = msk_s[SEQ - 1];
        SC += emissions[ebase + (size_t)last_ix * NT + tgl] * ml;
        SC += end_t[tgl] * ml;
        out_per_batch[b] = log_z - SC;
    }
}

// mean over batch -> scalar output
__global__ void crf_reduce_kernel(const float* __restrict__ pb, float* __restrict__ out)
{
    float v = pb[threadIdx.x];   // 256 threads, one per batch
    #pragma unroll
    for (int off = 32; off > 0; off >>= 1)
        v += __shfl_xor(v, off, 64);
    __shared__ float s4[4];
    if ((threadIdx.x & 63) == 0) s4[threadIdx.x >> 6] = v;
    __syncthreads();
    if (threadIdx.x == 0)
        out[0] = (s4[0] + s4[1] + s4[2] + s4[3]) * (1.0f / 256.0f);
}

extern "C" void kernel_launch(void* const* d_in, const int* in_sizes, int n_in,
                              void* d_out, int out_size, void* d_ws, size_t ws_size,
                              hipStream_t stream) {
    const float* emissions   = (const float*)d_in[0];
    const float* masks       = (const float*)d_in[1];
    const int*   tags        = (const int*)  d_in[2];
    const float* transitions = (const float*)d_in[3];
    const float* start_t     = (const float*)d_in[4];
    const float* end_t       = (const float*)d_in[5];
    float* per_batch = (float*)d_ws;

    crf_scan_kernel<<<NB, 256, 0, stream>>>(emissions, masks, tags, transitions,
                                            start_t, end_t, per_batch);
    crf_reduce_kernel<<<1, 256, 0, stream>>>(per_batch, (float*)d_out);
}